// Round 12
// baseline (78.758 us; speedup 1.0000x reference)
//
#include <hip/hip_runtime.h>
#include <math.h>

#define NF 1024
#define DIM 256
#define BATCH 2048
#define K 512              // interleaved (x^2, x) -> 2*DIM
#define BMF 16             // batch rows per fused block
#define KS 32              // k elems per step
#define NSTEP (K / KS)     // 16

// ws layout:
//   [0, 1MB)    : Bb bf16 [NSTEP][4(q)][NF][8]  (r9 layout, empirically best)
//   [1MB, +4KB) : c  float[NF]
#define WS_C_OFF (NF * K * 2)

typedef __attribute__((ext_vector_type(8))) short short8;   // 8 bf16
typedef __attribute__((ext_vector_type(4))) float f32x4;    // MFMA acc

__device__ __forceinline__ unsigned short f2bf(float f) {
    unsigned u = __float_as_uint(f);
    u += 0x7fffu + ((u >> 16) & 1u);       // RNE
    return (unsigned short)(u >> 16);
}

// async global->LDS, 16B per lane; LDS dest wave-uniform base + lane*16
__device__ __forceinline__ void gl_lds16(const ushort* g, ushort* l) {
    __builtin_amdgcn_global_load_lds(
        (const __attribute__((address_space(1))) void*)g,
        (__attribute__((address_space(3))) void*)l, 16, 0, 0);
}

// ---------------------------------------------------------------------------
// K1: unchanged from r9/r11 (q-major step-major Bb + c).
__global__ __launch_bounds__(256) void k_prep(const float* __restrict__ mu,
                                              const float* __restrict__ sigma,
                                              uint4* __restrict__ Bb4,
                                              float* __restrict__ c) {
    const int t = threadIdx.x;
    const int f = blockIdx.x * 4 + (t >> 6);
    const int sq = t & 63;                 // s = sq>>2, q = sq&3
    const float4 mv = *(const float4*)&mu[f * DIM + sq * 4];
    const float4 sv = *(const float4*)&sigma[f * DIM + sq * 4];

    uint4 pk; float cp = 0.f;
    {
        const float s2x = sv.x * sv.x;
        pk.x = (unsigned)f2bf(s2x) | ((unsigned)f2bf(-2.0f * s2x * mv.x) << 16);
        cp += s2x * mv.x * mv.x;
        const float s2y = sv.y * sv.y;
        pk.y = (unsigned)f2bf(s2y) | ((unsigned)f2bf(-2.0f * s2y * mv.y) << 16);
        cp += s2y * mv.y * mv.y;
        const float s2z = sv.z * sv.z;
        pk.z = (unsigned)f2bf(s2z) | ((unsigned)f2bf(-2.0f * s2z * mv.z) << 16);
        cp += s2z * mv.z * mv.z;
        const float s2w = sv.w * sv.w;
        pk.w = (unsigned)f2bf(s2w) | ((unsigned)f2bf(-2.0f * s2w * mv.w) << 16);
        cp += s2w * mv.w * mv.w;
    }
    // uint4 index: s*4096 + q*1024 + f
    Bb4[(sq >> 2) * 4096 + (sq & 3) * 1024 + f] = pk;

    #pragma unroll
    for (int off = 32; off > 0; off >>= 1) cp += __shfl_down(cp, off, 64);
    if ((t & 63) == 0) c[f] = cp;
}

// ---------------------------------------------------------------------------
// K2: fused GEMM + epilogue + FULL-ROW softmax normalization.
// 128 blocks x 1024 threads (16 waves/CU). Block = 16 rows x all 1024
// formulas; p stays in registers; out written once normalized.
//   A (16x512 bf16, 16 KB): XOR-swizzled LDS, shared by all 16 waves.
//   B: global_load_lds into PER-WAVE private LDS buffers (8 KB/wave,
//      2-step double buffer), counted s_waitcnt vmcnt(4) — no VGPR
//      round-trip, no barriers in the K-loop (waves fully independent).
//      gl_lds return (>=200cy) cannot beat the ds_reads (<=120cy) it
//      aliases; sched_barrier(0) pins issue order (rules #18/T4).
__global__ __launch_bounds__(1024, 1) void k_fused(const float* __restrict__ x,
                                                   const ushort* __restrict__ Bb,
                                                   const float* __restrict__ c,
                                                   const float* __restrict__ temp,
                                                   float* __restrict__ out) {
    const int t = threadIdx.x;
    const int w = t >> 6;          // wave 0..15
    const int lane = t & 63;
    const int m16 = lane & 15;
    const int q = lane >> 4;       // 0..3
    const int r0 = blockIdx.x * BMF;

    __shared__ __align__(16) ushort ldsA[BMF * K];        // 16 KB, swizzled
    __shared__ __align__(16) ushort ldsB[16 * 2 * 2048];  // 128 KB: per wave
                                                          // 2 bufs x 4 KB
    __shared__ float wsum[16][BMF];
    __shared__ float rowInv[BMF];

    // ---- pack A: 1024 units, one per thread ----
    {
        const int row = t >> 6, kc = t & 63;
        const float4 v = *(const float4*)&x[(r0 + row) * DIM + kc * 4];
        uint4 pk;
        pk.x = (unsigned)f2bf(v.x * v.x) | ((unsigned)f2bf(v.x) << 16);
        pk.y = (unsigned)f2bf(v.y * v.y) | ((unsigned)f2bf(v.y) << 16);
        pk.z = (unsigned)f2bf(v.z * v.z) | ((unsigned)f2bf(v.z) << 16);
        pk.w = (unsigned)f2bf(v.w * v.w) | ((unsigned)f2bf(v.w) << 16);
        *(uint4*)&ldsA[(row * 64 + (kc ^ (row & 7))) * 8] = pk;
    }

    f32x4 acc[4];
    #pragma unroll
    for (int ct = 0; ct < 4; ++ct) acc[ct] = (f32x4){0.f, 0.f, 0.f, 0.f};

    // per-lane B source: q-slot, formula fl = w*64 + m16;
    // ct tile -> +ct*128 elems; step s -> +s*32768 elems.
    const ushort* bp = Bb + q * (NF * 8) + (w * 64 + m16) * 8;
    ushort* myB = &ldsB[w * 4096];          // wave-private 8 KB (4096 ushorts)

#define ISSUE(sv, bufb)                                                     \
    _Pragma("unroll")                                                       \
    for (int ct = 0; ct < 4; ++ct)                                          \
        gl_lds16(bp + (sv) * (NF * KS) + ct * 128,                          \
                 myB + (bufb) * 2048 + ct * 512);

#define BCOMP(sv, bufb)                                                     \
    {                                                                       \
        const int kcq = (sv) * 4 + q;                                       \
        const short8 av =                                                   \
            *(const short8*)&ldsA[(m16 * 64 + (kcq ^ (m16 & 7))) * 8];      \
        _Pragma("unroll")                                                   \
        for (int ct = 0; ct < 4; ++ct) {                                    \
            const short8 bv = *(const short8*)&myB[(bufb) * 2048 +          \
                                                   ct * 512 + lane * 8];    \
            acc[ct] = __builtin_amdgcn_mfma_f32_16x16x32_bf16(              \
                av, bv, acc[ct], 0, 0, 0);                                  \
        }                                                                   \
    }

    __syncthreads();   // ldsA ready; also drains A-pack vmem (vmcnt -> 0)

    // prologue: steps 0,1 in flight (8 outstanding gl_lds)
    ISSUE(0, 0) ISSUE(1, 1)

    // ---- K loop: barrier-free; per-wave counted-vmcnt pipeline ----
    #pragma unroll 1
    for (int g = 0; g < 7; ++g) {
        const int s = g * 2;
        asm volatile("s_waitcnt vmcnt(4)" ::: "memory");   // step s landed
        __builtin_amdgcn_sched_barrier(0);
        BCOMP(s, 0)
        __builtin_amdgcn_sched_barrier(0);                 // reads issued
        ISSUE(s + 2, 0)
        asm volatile("s_waitcnt vmcnt(4)" ::: "memory");   // step s+1 landed
        __builtin_amdgcn_sched_barrier(0);
        BCOMP(s + 1, 1)
        __builtin_amdgcn_sched_barrier(0);
        ISSUE(s + 3, 1)
    }
    // tail: steps 14,15 (no further issues)
    asm volatile("s_waitcnt vmcnt(4)" ::: "memory");
    __builtin_amdgcn_sched_barrier(0);
    BCOMP(14, 0)
    asm volatile("s_waitcnt vmcnt(0)" ::: "memory");
    __builtin_amdgcn_sched_barrier(0);
    BCOMP(15, 1)

#undef ISSUE
#undef BCOMP

    // ---- epilogue: p = exp(g*exp(-dist)) in registers; wave row-sums ----
    const float g = 1.0f / (1.0f + __expf(-temp[0]));
    float s4[4] = {0.f, 0.f, 0.f, 0.f};
    #pragma unroll
    for (int ct = 0; ct < 4; ++ct) {
        const float cn = c[w * 64 + ct * 16 + m16];
        #pragma unroll
        for (int i = 0; i < 4; ++i) {
            const float dist2 = acc[ct][i] + cn;
            const float dist = sqrtf(fmaxf(dist2, 0.0f));
            const float p = __expf(g * __expf(-dist));
            acc[ct][i] = p;
            s4[i] += p;
        }
    }
    #pragma unroll
    for (int i = 0; i < 4; ++i) {
        #pragma unroll
        for (int mask = 1; mask < 16; mask <<= 1)
            s4[i] += __shfl_xor(s4[i], mask, 64);
    }
    if (m16 == 0) {
        #pragma unroll
        for (int i = 0; i < 4; ++i) wsum[w][q * 4 + i] = s4[i];
    }
    __syncthreads();
    if (t < BMF) {
        float ssum = 0.f;
        #pragma unroll
        for (int ww = 0; ww < 16; ++ww) ssum += wsum[ww][t];
        rowInv[t] = 1.0f / ssum;
    }
    __syncthreads();

    // ---- normalize in-register p, single coalesced out write ----
    float inv[4];
    #pragma unroll
    for (int i = 0; i < 4; ++i) inv[i] = rowInv[q * 4 + i];
    #pragma unroll
    for (int ct = 0; ct < 4; ++ct) {
        const int fcol = w * 64 + ct * 16 + m16;
        #pragma unroll
        for (int i = 0; i < 4; ++i)
            out[(r0 + q * 4 + i) * NF + fcol] = acc[ct][i] * inv[i];
    }
}

extern "C" void kernel_launch(void* const* d_in, const int* in_sizes, int n_in,
                              void* d_out, int out_size, void* d_ws, size_t ws_size,
                              hipStream_t stream) {
    const float* x     = (const float*)d_in[0];
    const float* mu    = (const float*)d_in[1];
    const float* sigma = (const float*)d_in[2];
    const float* temp  = (const float*)d_in[3];
    float* out = (float*)d_out;

    char* ws = (char*)d_ws;
    ushort* Bb = (ushort*)ws;
    float*  c  = (float*)(ws + WS_C_OFF);

    k_prep<<<NF / 4, 256, 0, stream>>>(mu, sigma, (uint4*)Bb, c);
    k_fused<<<BATCH / BMF, 1024, 0, stream>>>(x, Bb, c, temp, out);
}

// Round 13
// 75.400 us; speedup vs baseline: 1.0445x; 1.0445x over previous
//
#include <hip/hip_runtime.h>
#include <math.h>

#define NF 1024
#define DIM 256
#define BATCH 2048
#define K 512              // interleaved (x^2, x) -> 2*DIM
#define BMF 16             // batch rows per fused block
#define KS 32              // k elems per step
#define NSTEP (K / KS)     // 16

// ws layout:
//   [0, 1MB)    : Bb bf16 [NSTEP][4(q)][NF][8]  (step-major: each lane's
//                 per-step fragment is a contiguous 16B dwordx4; lanes
//                 m16=0..15 form contiguous 256B segments)
//   [1MB, +4KB) : c  float[NF]
#define WS_C_OFF (NF * K * 2)

typedef __attribute__((ext_vector_type(8))) short short8;   // 8 bf16
typedef __attribute__((ext_vector_type(4))) float f32x4;    // MFMA acc

__device__ __forceinline__ unsigned short f2bf(float f) {
    unsigned u = __float_as_uint(f);
    u += 0x7fffu + ((u >> 16) & 1u);       // RNE
    return (unsigned short)(u >> 16);
}

// ---------------------------------------------------------------------------
// K1: 256 blocks x 256 threads. Wave = one formula f; lane sq = (s,q) pair
// handles dims d0 = sq*4 .. +3. Fully-coalesced float4 loads, one uint4
// store into step-major Bb. c[f] via in-wave shuffle reduce.
__global__ __launch_bounds__(256) void k_prep(const float* __restrict__ mu,
                                              const float* __restrict__ sigma,
                                              uint4* __restrict__ Bb4,
                                              float* __restrict__ c) {
    const int t = threadIdx.x;
    const int f = blockIdx.x * 4 + (t >> 6);
    const int sq = t & 63;                 // s = sq>>2, q = sq&3
    const float4 mv = *(const float4*)&mu[f * DIM + sq * 4];
    const float4 sv = *(const float4*)&sigma[f * DIM + sq * 4];

    uint4 pk; float cp = 0.f;
    {
        const float s2x = sv.x * sv.x;
        pk.x = (unsigned)f2bf(s2x) | ((unsigned)f2bf(-2.0f * s2x * mv.x) << 16);
        cp += s2x * mv.x * mv.x;
        const float s2y = sv.y * sv.y;
        pk.y = (unsigned)f2bf(s2y) | ((unsigned)f2bf(-2.0f * s2y * mv.y) << 16);
        cp += s2y * mv.y * mv.y;
        const float s2z = sv.z * sv.z;
        pk.z = (unsigned)f2bf(s2z) | ((unsigned)f2bf(-2.0f * s2z * mv.z) << 16);
        cp += s2z * mv.z * mv.z;
        const float s2w = sv.w * sv.w;
        pk.w = (unsigned)f2bf(s2w) | ((unsigned)f2bf(-2.0f * s2w * mv.w) << 16);
        cp += s2w * mv.w * mv.w;
    }
    // uint4 index: s*4096 + q*1024 + f
    Bb4[(sq >> 2) * 4096 + (sq & 3) * 1024 + f] = pk;

    #pragma unroll
    for (int off = 32; off > 0; off >>= 1) cp += __shfl_down(cp, off, 64);
    if ((t & 63) == 0) c[f] = cp;
}

// ---------------------------------------------------------------------------
// K2: fused GEMM + epilogue + FULL-ROW softmax normalization.
// 128 blocks x 1024 threads (16 waves/CU). Block = 16 batch rows x ALL 1024
// formulas -> denominator is block-local: p stays in registers, out written
// exactly ONCE (normalized). No k_norm, no fences, no cross-block sync.
//   A (16x512 bf16, 16 KB): XOR-swizzled LDS, shared by all 16 waves.
//   B: global->reg double-buffered dwordx4 from step-major Bb (barrier-free
//      K-loop); wave w owns formulas [w*64, +64) as 4 ct tiles.
// Probe matrix (r7-r12): TLP/depth/layout/DMA all neutral-or-worse ->
// this config is the empirical per-CU streaming floor.
__global__ __launch_bounds__(1024, 1) void k_fused(const float* __restrict__ x,
                                                   const ushort* __restrict__ Bb,
                                                   const float* __restrict__ c,
                                                   const float* __restrict__ temp,
                                                   float* __restrict__ out) {
    const int t = threadIdx.x;
    const int w = t >> 6;          // wave 0..15
    const int lane = t & 63;
    const int m16 = lane & 15;
    const int q = lane >> 4;       // 0..3
    const int r0 = blockIdx.x * BMF;

    __shared__ __align__(16) ushort ldsA[BMF * K];      // 16 KB, swizzled
    __shared__ float wsum[16][BMF];
    __shared__ float rowInv[BMF];

    // ---- pack A: 1024 units, one per thread ----
    {
        const int row = t >> 6, kc = t & 63;
        const float4 v = *(const float4*)&x[(r0 + row) * DIM + kc * 4];
        uint4 pk;
        pk.x = (unsigned)f2bf(v.x * v.x) | ((unsigned)f2bf(v.x) << 16);
        pk.y = (unsigned)f2bf(v.y * v.y) | ((unsigned)f2bf(v.y) << 16);
        pk.z = (unsigned)f2bf(v.z * v.z) | ((unsigned)f2bf(v.z) << 16);
        pk.w = (unsigned)f2bf(v.w * v.w) | ((unsigned)f2bf(v.w) << 16);
        *(uint4*)&ldsA[(row * 64 + (kc ^ (row & 7))) * 8] = pk;
    }

    f32x4 acc[4];
    #pragma unroll
    for (int ct = 0; ct < 4; ++ct) acc[ct] = (f32x4){0.f, 0.f, 0.f, 0.f};

    // per-lane B pointer: q-slot, formula fl = w*64 + m16;
    // ct tile -> +ct*128 elems; step s -> +s*32768 elems.
    const ushort* bp = Bb + q * (NF * 8) + (w * 64 + m16) * 8;

    // prologue: step 0 into bA
    short8 bA[4], bB[4];
    #pragma unroll
    for (int ct = 0; ct < 4; ++ct)
        bA[ct] = *(const short8*)(bp + ct * 128);

    __syncthreads();   // ldsA ready (only pre-epilogue barrier)

    // ---- K loop: barrier-free, reg double-buffered B ----
    #pragma unroll 1
    for (int s = 0; s < NSTEP; s += 2) {
        #pragma unroll
        for (int ct = 0; ct < 4; ++ct)
            bB[ct] = *(const short8*)(bp + (s + 1) * (NF * KS) + ct * 128);
        {
            const int kcq = s * 4 + q;
            const short8 av = *(const short8*)&ldsA[(m16 * 64 + (kcq ^ (m16 & 7))) * 8];
            #pragma unroll
            for (int ct = 0; ct < 4; ++ct)
                acc[ct] = __builtin_amdgcn_mfma_f32_16x16x32_bf16(av, bA[ct], acc[ct], 0, 0, 0);
        }
        if (s + 2 < NSTEP) {
            #pragma unroll
            for (int ct = 0; ct < 4; ++ct)
                bA[ct] = *(const short8*)(bp + (s + 2) * (NF * KS) + ct * 128);
        }
        {
            const int kcq = (s + 1) * 4 + q;
            const short8 av = *(const short8*)&ldsA[(m16 * 64 + (kcq ^ (m16 & 7))) * 8];
            #pragma unroll
            for (int ct = 0; ct < 4; ++ct)
                acc[ct] = __builtin_amdgcn_mfma_f32_16x16x32_bf16(av, bB[ct], acc[ct], 0, 0, 0);
        }
    }

    // ---- epilogue: p = exp(g*exp(-dist)) in registers; wave row-sums ----
    const float g = 1.0f / (1.0f + __expf(-temp[0]));
    float s4[4] = {0.f, 0.f, 0.f, 0.f};
    #pragma unroll
    for (int ct = 0; ct < 4; ++ct) {
        const float cn = c[w * 64 + ct * 16 + m16];
        #pragma unroll
        for (int i = 0; i < 4; ++i) {
            const float dist2 = acc[ct][i] + cn;
            const float dist = sqrtf(fmaxf(dist2, 0.0f));
            const float p = __expf(g * __expf(-dist));
            acc[ct][i] = p;
            s4[i] += p;
        }
    }
    #pragma unroll
    for (int i = 0; i < 4; ++i) {
        #pragma unroll
        for (int mask = 1; mask < 16; mask <<= 1)
            s4[i] += __shfl_xor(s4[i], mask, 64);
    }
    if (m16 == 0) {
        #pragma unroll
        for (int i = 0; i < 4; ++i) wsum[w][q * 4 + i] = s4[i];
    }
    __syncthreads();
    if (t < BMF) {
        float ssum = 0.f;
        #pragma unroll
        for (int ww = 0; ww < 16; ++ww) ssum += wsum[ww][t];
        rowInv[t] = 1.0f / ssum;
    }
    __syncthreads();

    // ---- normalize in-register p, single coalesced out write ----
    float inv[4];
    #pragma unroll
    for (int i = 0; i < 4; ++i) inv[i] = rowInv[q * 4 + i];
    #pragma unroll
    for (int ct = 0; ct < 4; ++ct) {
        const int fcol = w * 64 + ct * 16 + m16;
        #pragma unroll
        for (int i = 0; i < 4; ++i)
            out[(r0 + q * 4 + i) * NF + fcol] = acc[ct][i] * inv[i];
    }
}

extern "C" void kernel_launch(void* const* d_in, const int* in_sizes, int n_in,
                              void* d_out, int out_size, void* d_ws, size_t ws_size,
                              hipStream_t stream) {
    const float* x     = (const float*)d_in[0];
    const float* mu    = (const float*)d_in[1];
    const float* sigma = (const float*)d_in[2];
    const float* temp  = (const float*)d_in[3];
    float* out = (float*)d_out;

    char* ws = (char*)d_ws;
    ushort* Bb = (ushort*)ws;
    float*  c  = (float*)(ws + WS_C_OFF);

    k_prep<<<NF / 4, 256, 0, stream>>>(mu, sigma, (uint4*)Bb, c);
    k_fused<<<BATCH / BMF, 1024, 0, stream>>>(x, Bb, c, temp, out);
}